// Round 1
// baseline (570.879 us; speedup 1.0000x reference)
//
#include <hip/hip_runtime.h>
#include <hip/hip_bf16.h>

#define NN 30000          // N_H == N_O
#define DEG 16
#define DIN 256
#define NHEAD 4
#define DHD 64
#define ZEL (NN * 256)    // 7,680,000 floats per node-feature matrix

// ---------------------------------------------------------------------------
// u[h*256+d] = sum_k W[h][d][k] * a[h*128 + 64 + k]   (dst-score projection)
__global__ void prep_u(const float* __restrict__ W, const float* __restrict__ a,
                       float* __restrict__ u) {
    int t = threadIdx.x;
    for (int idx = t; idx < NHEAD * DIN; idx += blockDim.x) {
        int h = idx >> 8, d = idx & 255;
        const float* wp = W + (h * DIN + d) * DHD;
        const float* ap = a + h * 128 + 64;
        float s = 0.f;
        #pragma unroll 8
        for (int k = 0; k < DHD; ++k) s += wp[k] * ap[k];
        u[idx] = s;
    }
}

// ---------------------------------------------------------------------------
// z[n, h*64+k] = sum_d concat(f1[n],f2[n])[d] * W[h][d][k]
// 32 rows/block, 256 threads = 4 waves x (8 rows x 256 cols), A in LDS.
__global__ __launch_bounds__(256)
void node_gemm(const float* __restrict__ f1, const float* __restrict__ f2,
               const float* __restrict__ W, float* __restrict__ z) {
    __shared__ float As[32][256];
    int t = threadIdx.x;
    int row0 = blockIdx.x * 32;
    #pragma unroll
    for (int i = 0; i < 8; ++i) {
        int flat = i * 1024 + t * 4;
        int r = flat >> 8, c = flat & 255;
        int n = row0 + r; if (n >= NN) n = NN - 1;
        const float* src = (c < 128) ? (f1 + n * 128 + c) : (f2 + n * 128 + (c - 128));
        *reinterpret_cast<float4*>(&As[r][c]) = *reinterpret_cast<const float4*>(src);
    }
    __syncthreads();
    int lane = t & 63, wv = t >> 6;
    int rbase = wv * 8;
    int c = lane * 4;
    int h = c >> 6, k = c & 63;
    const float* Wc = W + h * (DIN * DHD) + k;   // element (d): Wc[d*64 + 0..3]
    float4 acc[8];
    #pragma unroll
    for (int r = 0; r < 8; ++r) acc[r] = make_float4(0.f, 0.f, 0.f, 0.f);
    for (int d = 0; d < DIN; d += 4) {
        float4 b0 = *reinterpret_cast<const float4*>(Wc + (d + 0) * DHD);
        float4 b1 = *reinterpret_cast<const float4*>(Wc + (d + 1) * DHD);
        float4 b2 = *reinterpret_cast<const float4*>(Wc + (d + 2) * DHD);
        float4 b3 = *reinterpret_cast<const float4*>(Wc + (d + 3) * DHD);
        #pragma unroll
        for (int r = 0; r < 8; ++r) {
            float4 a4 = *reinterpret_cast<const float4*>(&As[rbase + r][d]);
            acc[r].x += a4.x * b0.x + a4.y * b1.x + a4.z * b2.x + a4.w * b3.x;
            acc[r].y += a4.x * b0.y + a4.y * b1.y + a4.z * b2.y + a4.w * b3.y;
            acc[r].z += a4.x * b0.z + a4.y * b1.z + a4.z * b2.z + a4.w * b3.z;
            acc[r].w += a4.x * b0.w + a4.y * b1.w + a4.z * b2.w + a4.w * b3.w;
        }
    }
    #pragma unroll
    for (int r = 0; r < 8; ++r) {
        int n = row0 + rbase + r;
        if (n < NN) *reinterpret_cast<float4*>(z + n * 256 + c) = acc[r];
    }
}

// ---------------------------------------------------------------------------
// Per node (one wave): s_src[n,h] = sum_k zs[n,h*64+k]*a1[h,k]
//                      s_src2 from z2,a2 ; s_dst = dsth . u1[h] ; s_dst2 = dsth . u2[h]
__global__ __launch_bounds__(256)
void scores_kernel(const float* __restrict__ zs, const float* __restrict__ z2,
                   const float* __restrict__ fo1, const float* __restrict__ fo2,
                   const float* __restrict__ a1, const float* __restrict__ a2,
                   const float* __restrict__ u1, const float* __restrict__ u2,
                   float* __restrict__ s_src, float* __restrict__ s_dst,
                   float* __restrict__ s_src2, float* __restrict__ s_dst2) {
    int wid = (blockIdx.x * blockDim.x + threadIdx.x) >> 6;
    int lane = threadIdx.x & 63;
    if (wid >= NN) return;
    int h = lane >> 4;
    int c = lane * 4;
    int k = c & 63;

    float4 zv = *reinterpret_cast<const float4*>(zs + wid * 256 + c);
    const float* a1h = a1 + h * 128 + k;
    float p = zv.x * a1h[0] + zv.y * a1h[1] + zv.z * a1h[2] + zv.w * a1h[3];
    #pragma unroll
    for (int m = 1; m < 16; m <<= 1) p += __shfl_xor(p, m, 64);
    if ((lane & 15) == 0) s_src[wid * 4 + h] = p;

    float4 z2v = *reinterpret_cast<const float4*>(z2 + wid * 256 + c);
    const float* a2h = a2 + h * 128 + k;
    float q = z2v.x * a2h[0] + z2v.y * a2h[1] + z2v.z * a2h[2] + z2v.w * a2h[3];
    #pragma unroll
    for (int m = 1; m < 16; m <<= 1) q += __shfl_xor(q, m, 64);
    if ((lane & 15) == 0) s_src2[wid * 4 + h] = q;

    const float* dsrc = (c < 128) ? (fo1 + wid * 128 + c) : (fo2 + wid * 128 + (c - 128));
    float4 dv = *reinterpret_cast<const float4*>(dsrc);
    float pd1[4], pd2[4];
    #pragma unroll
    for (int hh = 0; hh < 4; ++hh) {
        const float* u1p = u1 + hh * 256 + c;
        const float* u2p = u2 + hh * 256 + c;
        pd1[hh] = dv.x * u1p[0] + dv.y * u1p[1] + dv.z * u1p[2] + dv.w * u1p[3];
        pd2[hh] = dv.x * u2p[0] + dv.y * u2p[1] + dv.z * u2p[2] + dv.w * u2p[3];
    }
    #pragma unroll
    for (int m = 1; m < 64; m <<= 1) {
        #pragma unroll
        for (int hh = 0; hh < 4; ++hh) {
            pd1[hh] += __shfl_xor(pd1[hh], m, 64);
            pd2[hh] += __shfl_xor(pd2[hh], m, 64);
        }
    }
    if (lane == 0) {
        #pragma unroll
        for (int hh = 0; hh < 4; ++hh) {
            s_dst[wid * 4 + hh] = pd1[hh];
            s_dst2[wid * 4 + hh] = pd2[hh];
        }
    }
}

// ---------------------------------------------------------------------------
// One wave per dst node: 16 contiguous edges, 4 heads. lane = h*16 + e.
__global__ __launch_bounds__(256)
void agg_kernel(const float* __restrict__ z, const float* __restrict__ s_src,
                const float* __restrict__ s_dst, const int* __restrict__ esrc,
                float* __restrict__ out) {
    int wid = (blockIdx.x * blockDim.x + threadIdx.x) >> 6;
    int lane = threadIdx.x & 63;
    if (wid >= NN) return;
    int h = lane >> 4;
    int e = lane & 15;
    int src = esrc[wid * 16 + e];
    float x = s_src[src * 4 + h] + s_dst[wid * 4 + h];
    x = (x >= 0.f) ? x : 0.01f * x;
    float m = x;
    #pragma unroll
    for (int d = 1; d < 16; d <<= 1) m = fmaxf(m, __shfl_xor(m, d, 64));
    float p = __expf(x - m);
    float s = p;
    #pragma unroll
    for (int d = 1; d < 16; d <<= 1) s += __shfl_xor(s, d, 64);
    float alpha = p / s;

    int c = h * 64 + e * 4;          // reuse e as the col sub-index
    int gbase = lane & 48;
    float4 acc = make_float4(0.f, 0.f, 0.f, 0.f);
    #pragma unroll
    for (int t = 0; t < 16; ++t) {
        float a = __shfl(alpha, gbase | t, 64);
        int sidx = __shfl(src, gbase | t, 64);
        float4 v = *reinterpret_cast<const float4*>(z + sidx * 256 + c);
        acc.x += a * v.x; acc.y += a * v.y; acc.z += a * v.z; acc.w += a * v.w;
    }
    *reinterpret_cast<float4*>(out + wid * 256 + c) = acc;
}

// ---------------------------------------------------------------------------
// rows R=0..59999: R=2n+e, row = (e? h2 : h1)[n]. t = tanh(row@Wp1 + bp1);
// partial w[e] += t . wp2 ; block-reduce ; atomicAdd.
__global__ __launch_bounds__(256)
void proj_kernel(const float* __restrict__ h1, const float* __restrict__ h2,
                 const float* __restrict__ Wp, const float* __restrict__ bp,
                 const float* __restrict__ wp2, float* __restrict__ wacc) {
    __shared__ float As[32][256];
    __shared__ float red[2][4];
    int t = threadIdx.x;
    int row0 = blockIdx.x * 32;
    #pragma unroll
    for (int i = 0; i < 8; ++i) {
        int flat = i * 1024 + t * 4;
        int r = flat >> 8, c = flat & 255;
        int R = row0 + r;
        const float* src = ((R & 1) ? h2 : h1) + (R >> 1) * 256 + c;
        *reinterpret_cast<float4*>(&As[r][c]) = *reinterpret_cast<const float4*>(src);
    }
    __syncthreads();
    int lane = t & 63, wv = t >> 6;
    int rbase = wv * 8;
    int c = lane * 4;
    const float* Wc = Wp + c;   // element (d): Wc[d*256 + 0..3]
    float4 acc[8];
    #pragma unroll
    for (int r = 0; r < 8; ++r) acc[r] = make_float4(0.f, 0.f, 0.f, 0.f);
    for (int d = 0; d < 256; d += 4) {
        float4 b0 = *reinterpret_cast<const float4*>(Wc + (d + 0) * 256);
        float4 b1 = *reinterpret_cast<const float4*>(Wc + (d + 1) * 256);
        float4 b2 = *reinterpret_cast<const float4*>(Wc + (d + 2) * 256);
        float4 b3 = *reinterpret_cast<const float4*>(Wc + (d + 3) * 256);
        #pragma unroll
        for (int r = 0; r < 8; ++r) {
            float4 a4 = *reinterpret_cast<const float4*>(&As[rbase + r][d]);
            acc[r].x += a4.x * b0.x + a4.y * b1.x + a4.z * b2.x + a4.w * b3.x;
            acc[r].y += a4.x * b0.y + a4.y * b1.y + a4.z * b2.y + a4.w * b3.y;
            acc[r].z += a4.x * b0.z + a4.y * b1.z + a4.z * b2.z + a4.w * b3.z;
            acc[r].w += a4.x * b0.w + a4.y * b1.w + a4.z * b2.w + a4.w * b3.w;
        }
    }
    float4 bpv = *reinterpret_cast<const float4*>(bp + c);
    float4 wv4 = *reinterpret_cast<const float4*>(wp2 + c);
    float part[2] = {0.f, 0.f};
    #pragma unroll
    for (int r = 0; r < 8; ++r) {
        int R = row0 + rbase + r;
        float sv = tanhf(acc[r].x + bpv.x) * wv4.x + tanhf(acc[r].y + bpv.y) * wv4.y
                 + tanhf(acc[r].z + bpv.z) * wv4.z + tanhf(acc[r].w + bpv.w) * wv4.w;
        part[R & 1] += sv;
    }
    #pragma unroll
    for (int d = 1; d < 64; d <<= 1) {
        part[0] += __shfl_xor(part[0], d, 64);
        part[1] += __shfl_xor(part[1], d, 64);
    }
    if (lane == 0) { red[0][wv] = part[0]; red[1][wv] = part[1]; }
    __syncthreads();
    if (t == 0) {
        atomicAdd(wacc + 0, red[0][0] + red[0][1] + red[0][2] + red[0][3]);
        atomicAdd(wacc + 1, red[1][0] + red[1][1] + red[1][2] + red[1][3]);
    }
}

// ---------------------------------------------------------------------------
__global__ __launch_bounds__(256)
void combine_kernel(const float* __restrict__ h1, const float* __restrict__ h2,
                    const float* __restrict__ wacc, float* __restrict__ out) {
    int idx = blockIdx.x * blockDim.x + threadIdx.x;   // over NN*64 float4s
    if (idx >= NN * 64) return;
    float w0 = wacc[0] * (1.f / 30000.f), w1 = wacc[1] * (1.f / 30000.f);
    float mx = fmaxf(w0, w1);
    float e0 = __expf(w0 - mx), e1 = __expf(w1 - mx);
    float inv = 1.f / (e0 + e1);
    float b0 = e0 * inv, b1 = e1 * inv;
    float4 v1 = *reinterpret_cast<const float4*>(h1 + idx * 4);
    float4 v2 = *reinterpret_cast<const float4*>(h2 + idx * 4);
    float4 o = make_float4(b0 * v1.x + b1 * v2.x, b0 * v1.y + b1 * v2.y,
                           b0 * v1.z + b1 * v2.z, b0 * v1.w + b1 * v2.w);
    *reinterpret_cast<float4*>(out + idx * 4) = o;
}

// ---------------------------------------------------------------------------
extern "C" void kernel_launch(void* const* d_in, const int* in_sizes, int n_in,
                              void* d_out, int out_size, void* d_ws, size_t ws_size,
                              hipStream_t stream) {
    const float* embed_h = (const float*)d_in[0];
    const float* gru_h   = (const float*)d_in[1];
    const float* embed_o = (const float*)d_in[2];
    const float* gru_o   = (const float*)d_in[3];
    const float* W_src1  = (const float*)d_in[4];
    const float* W_dst1  = (const float*)d_in[5];
    const float* a1      = (const float*)d_in[6];
    const float* W_in2   = (const float*)d_in[7];
    const float* a2      = (const float*)d_in[8];
    const float* Wp1     = (const float*)d_in[9];
    const float* bp1     = (const float*)d_in[10];
    const float* wp2     = (const float*)d_in[11];
    const int*   e1_src  = (const int*)d_in[12];
    const int*   e2_src  = (const int*)d_in[14];
    float* out = (float*)d_out;

    float* ws = (float*)d_ws;
    float* zs    = ws;                 // 7.68M floats (aliased as h2 later)
    float* z2    = ws + (size_t)ZEL;
    float* h1    = ws + (size_t)2 * ZEL;
    float* h2    = zs;                 // reuse: z_s dead after agg layer 1
    float* ssrc  = ws + (size_t)3 * ZEL;
    float* sdst  = ssrc + NN * 4;
    float* ssrc2 = ssrc + NN * 8;
    float* sdst2 = ssrc + NN * 12;
    float* u1    = ssrc + NN * 16;
    float* u2    = u1 + 1024;
    float* wacc  = u2 + 1024;

    prep_u<<<1, 256, 0, stream>>>(W_dst1, a1, u1);
    prep_u<<<1, 256, 0, stream>>>(W_in2, a2, u2);

    int gemm_blocks = (NN + 31) / 32;
    node_gemm<<<gemm_blocks, 256, 0, stream>>>(embed_h, gru_h, W_src1, zs);
    node_gemm<<<gemm_blocks, 256, 0, stream>>>(embed_o, gru_o, W_in2, z2);

    int wave_blocks = (NN * 64 + 255) / 256;
    scores_kernel<<<wave_blocks, 256, 0, stream>>>(zs, z2, embed_o, gru_o, a1, a2,
                                                   u1, u2, ssrc, sdst, ssrc2, sdst2);

    agg_kernel<<<wave_blocks, 256, 0, stream>>>(zs, ssrc, sdst, e1_src, h1);
    agg_kernel<<<wave_blocks, 256, 0, stream>>>(z2, ssrc2, sdst2, e2_src, h2);

    hipMemsetAsync(wacc, 0, 2 * sizeof(float), stream);
    proj_kernel<<<60000 / 32, 256, 0, stream>>>(h1, h2, Wp1, bp1, wp2, wacc);

    combine_kernel<<<(NN * 64 + 255) / 256, 256, 0, stream>>>(h1, h2, wacc, out);
}

// Round 4
// 497.576 us; speedup vs baseline: 1.1473x; 1.1473x over previous
//
#include <hip/hip_runtime.h>
#include <hip/hip_bf16.h>

#define NN 30000          // N_H == N_O
#define DEG 16
#define ZEL (NN * 256)    // floats per node-feature matrix

typedef __attribute__((ext_vector_type(8))) short bf16x8_t;
typedef __attribute__((ext_vector_type(4))) float f32x4_t;

// ---- bf16 bit helpers (RNE), no __bf16 type dependence -------------------
__device__ __forceinline__ unsigned short f2bf(float x) {
    unsigned u = __float_as_uint(x);
    return (unsigned short)((u + 0x7FFFu + ((u >> 16) & 1u)) >> 16);
}
__device__ __forceinline__ float bf2f(unsigned short b) {
    return __uint_as_float(((unsigned)b) << 16);
}

// ---------------------------------------------------------------------------
// Convert weight matrix to MFMA-frag-friendly hi/lo bf16 layout.
// Logical B[d][c], d = K-dim (0..255), c = N-dim (0..255).
//   isWp==0: B[d][c] = W[h][d][k], c = h*64+k   (W: [4][256][64])
//   isWp==1: B[d][c] = W[d*256+c]               (Wp1: [256][256])
// Stored: Bf[(d>>5)*8192 + c*32 + (d&31)]  (K-step slabs of 32)
__global__ void convert_w(const float* __restrict__ W, int isWp,
                          unsigned short* __restrict__ Bhi,
                          unsigned short* __restrict__ Blo) {
    int idx = blockIdx.x * 256 + threadIdx.x;
    if (idx >= 65536) return;
    int d = idx >> 8, c = idx & 255;
    float x;
    if (isWp) x = W[d * 256 + c];
    else { int h = c >> 6, k = c & 63; x = W[h * 16384 + d * 64 + k]; }
    unsigned short hh = f2bf(x);
    unsigned short ll = f2bf(x - bf2f(hh));
    int o = (d >> 5) * 8192 + c * 32 + (d & 31);
    Bhi[o] = hh; Blo[o] = ll;
}

// ---------------------------------------------------------------------------
// u[h*256+d] = sum_k W[h][d][k] * a[h*128 + 64 + k]
__global__ void prep_u(const float* __restrict__ W, const float* __restrict__ a,
                       float* __restrict__ u) {
    int t = threadIdx.x;
    for (int idx = t; idx < 1024; idx += blockDim.x) {
        int h = idx >> 8, d = idx & 255;
        const float* wp = W + (h * 256 + d) * 64;
        const float* ap = a + h * 128 + 64;
        float s = 0.f;
        #pragma unroll 8
        for (int k = 0; k < 64; ++k) s += wp[k] * ap[k];
        u[idx] = s;
    }
}

// ---------------------------------------------------------------------------
// z[n, :256] = concat(f1[n],f2[n]) @ B   via bf16-split MFMA 16x16x32.
// Wave = 16 rows x 256 cols. Block = 4 waves = 64 rows. No LDS.
__global__ __launch_bounds__(256)
void gemm_nodes(const float* __restrict__ f1, const float* __restrict__ f2,
                const unsigned short* __restrict__ Bhi,
                const unsigned short* __restrict__ Blo,
                float* __restrict__ z) {
    int t = threadIdx.x, l = t & 63, wv = t >> 6;
    int row0 = blockIdx.x * 64 + wv * 16;
    int arow = row0 + (l & 15); if (arow >= NN) arow = NN - 1;
    int g = l >> 4;
    f32x4_t acc[16];
    #pragma unroll
    for (int ct = 0; ct < 16; ++ct) acc[ct] = (f32x4_t){0.f, 0.f, 0.f, 0.f};

    for (int kk = 0; kk < 8; ++kk) {
        int k0 = kk * 32 + g * 8;
        const float* ap = (k0 < 128) ? (f1 + arow * 128 + k0)
                                     : (f2 + arow * 128 + (k0 - 128));
        float4 x0 = *reinterpret_cast<const float4*>(ap);
        float4 x1 = *reinterpret_cast<const float4*>(ap + 4);
        bf16x8_t ah, al;
        {
            float xs[8] = {x0.x, x0.y, x0.z, x0.w, x1.x, x1.y, x1.z, x1.w};
            #pragma unroll
            for (int j = 0; j < 8; ++j) {
                unsigned short h = f2bf(xs[j]);
                ah[j] = (short)h;
                al[j] = (short)f2bf(xs[j] - bf2f(h));
            }
        }
        const unsigned short* bb = Bhi + kk * 8192 + (l & 15) * 32 + g * 8;
        const unsigned short* bL = Blo + kk * 8192 + (l & 15) * 32 + g * 8;
        #pragma unroll
        for (int ct = 0; ct < 16; ++ct) {
            bf16x8_t bhv = *reinterpret_cast<const bf16x8_t*>(bb + ct * 512);
            bf16x8_t blv = *reinterpret_cast<const bf16x8_t*>(bL + ct * 512);
            acc[ct] = __builtin_amdgcn_mfma_f32_16x16x32_bf16(ah, bhv, acc[ct], 0, 0, 0);
            acc[ct] = __builtin_amdgcn_mfma_f32_16x16x32_bf16(ah, blv, acc[ct], 0, 0, 0);
            acc[ct] = __builtin_amdgcn_mfma_f32_16x16x32_bf16(al, bhv, acc[ct], 0, 0, 0);
        }
    }
    int r0 = row0 + g * 4;
    #pragma unroll
    for (int ct = 0; ct < 16; ++ct) {
        int col = ct * 16 + (l & 15);
        #pragma unroll
        for (int i = 0; i < 4; ++i) {
            int r = r0 + i;
            if (r < NN) z[r * 256 + col] = acc[ct][i];
        }
    }
}

// ---------------------------------------------------------------------------
// scores (unchanged from R1): per node (one wave).
__global__ __launch_bounds__(256)
void scores_kernel(const float* __restrict__ zs, const float* __restrict__ z2,
                   const float* __restrict__ fo1, const float* __restrict__ fo2,
                   const float* __restrict__ a1, const float* __restrict__ a2,
                   const float* __restrict__ u1, const float* __restrict__ u2,
                   float* __restrict__ s_src, float* __restrict__ s_dst,
                   float* __restrict__ s_src2, float* __restrict__ s_dst2) {
    int wid = (blockIdx.x * blockDim.x + threadIdx.x) >> 6;
    int lane = threadIdx.x & 63;
    if (wid >= NN) return;
    int h = lane >> 4;
    int c = lane * 4;
    int k = c & 63;

    float4 zv = *reinterpret_cast<const float4*>(zs + wid * 256 + c);
    const float* a1h = a1 + h * 128 + k;
    float p = zv.x * a1h[0] + zv.y * a1h[1] + zv.z * a1h[2] + zv.w * a1h[3];
    #pragma unroll
    for (int m = 1; m < 16; m <<= 1) p += __shfl_xor(p, m, 64);
    if ((lane & 15) == 0) s_src[wid * 4 + h] = p;

    float4 z2v = *reinterpret_cast<const float4*>(z2 + wid * 256 + c);
    const float* a2h = a2 + h * 128 + k;
    float q = z2v.x * a2h[0] + z2v.y * a2h[1] + z2v.z * a2h[2] + z2v.w * a2h[3];
    #pragma unroll
    for (int m = 1; m < 16; m <<= 1) q += __shfl_xor(q, m, 64);
    if ((lane & 15) == 0) s_src2[wid * 4 + h] = q;

    const float* dsrc = (c < 128) ? (fo1 + wid * 128 + c) : (fo2 + wid * 128 + (c - 128));
    float4 dv = *reinterpret_cast<const float4*>(dsrc);
    float pd1[4], pd2[4];
    #pragma unroll
    for (int hh = 0; hh < 4; ++hh) {
        const float* u1p = u1 + hh * 256 + c;
        const float* u2p = u2 + hh * 256 + c;
        pd1[hh] = dv.x * u1p[0] + dv.y * u1p[1] + dv.z * u1p[2] + dv.w * u1p[3];
        pd2[hh] = dv.x * u2p[0] + dv.y * u2p[1] + dv.z * u2p[2] + dv.w * u2p[3];
    }
    #pragma unroll
    for (int m = 1; m < 64; m <<= 1) {
        #pragma unroll
        for (int hh = 0; hh < 4; ++hh) {
            pd1[hh] += __shfl_xor(pd1[hh], m, 64);
            pd2[hh] += __shfl_xor(pd2[hh], m, 64);
        }
    }
    if (lane == 0) {
        #pragma unroll
        for (int hh = 0; hh < 4; ++hh) {
            s_dst[wid * 4 + hh] = pd1[hh];
            s_dst2[wid * 4 + hh] = pd2[hh];
        }
    }
}

// ---------------------------------------------------------------------------
// One wave per dst node. Output written as hi/lo bf16 (same bytes as f32).
__global__ __launch_bounds__(256)
void agg_kernel(const float* __restrict__ z, const float* __restrict__ s_src,
                const float* __restrict__ s_dst, const int* __restrict__ esrc,
                unsigned short* __restrict__ ohi, unsigned short* __restrict__ olo) {
    int wid = (blockIdx.x * blockDim.x + threadIdx.x) >> 6;
    int lane = threadIdx.x & 63;
    if (wid >= NN) return;
    int h = lane >> 4;
    int e = lane & 15;
    int src = esrc[wid * 16 + e];
    float x = s_src[src * 4 + h] + s_dst[wid * 4 + h];
    x = (x >= 0.f) ? x : 0.01f * x;
    float m = x;
    #pragma unroll
    for (int d = 1; d < 16; d <<= 1) m = fmaxf(m, __shfl_xor(m, d, 64));
    float p = __expf(x - m);
    float s = p;
    #pragma unroll
    for (int d = 1; d < 16; d <<= 1) s += __shfl_xor(s, d, 64);
    float alpha = p / s;

    int c = h * 64 + e * 4;
    int gbase = lane & 48;
    float4 acc = make_float4(0.f, 0.f, 0.f, 0.f);
    #pragma unroll
    for (int t = 0; t < 16; ++t) {
        float a = __shfl(alpha, gbase | t, 64);
        int sidx = __shfl(src, gbase | t, 64);
        float4 v = *reinterpret_cast<const float4*>(z + sidx * 256 + c);
        acc.x += a * v.x; acc.y += a * v.y; acc.z += a * v.z; acc.w += a * v.w;
    }
    int base = wid * 256 + c;
    ushort4 hv, lv;
    hv.x = f2bf(acc.x); lv.x = f2bf(acc.x - bf2f(hv.x));
    hv.y = f2bf(acc.y); lv.y = f2bf(acc.y - bf2f(hv.y));
    hv.z = f2bf(acc.z); lv.z = f2bf(acc.z - bf2f(hv.z));
    hv.w = f2bf(acc.w); lv.w = f2bf(acc.w - bf2f(hv.w));
    *reinterpret_cast<ushort4*>(ohi + base) = hv;
    *reinterpret_cast<ushort4*>(olo + base) = lv;
}

// ---------------------------------------------------------------------------
// Rows R=0..59999 (R=2n+e; e=0 -> h1[n], e=1 -> h2[n]) @ Wp1 -> tanh -> .wp2
// -> sum per e -> atomicAdd. Wave = 16 rows x 256 cols, bf16-split MFMA.
__global__ __launch_bounds__(256)
void gemm_proj(const unsigned short* __restrict__ hhi1, const unsigned short* __restrict__ hlo1,
               const unsigned short* __restrict__ hhi2, const unsigned short* __restrict__ hlo2,
               const unsigned short* __restrict__ Bhi, const unsigned short* __restrict__ Blo,
               const float* __restrict__ bp, const float* __restrict__ wp2v,
               float* __restrict__ wacc) {
    int t = threadIdx.x, l = t & 63, wv = t >> 6;
    int row0 = blockIdx.x * 64 + wv * 16;
    int R = row0 + (l & 15); if (R >= 2 * NN) R = 2 * NN - 1;
    int e = R & 1, n = R >> 1;
    const unsigned short* Ahi = (e ? hhi2 : hhi1) + n * 256;
    const unsigned short* Alo = (e ? hlo2 : hlo1) + n * 256;
    int g = l >> 4;
    f32x4_t acc[16];
    #pragma unroll
    for (int ct = 0; ct < 16; ++ct) acc[ct] = (f32x4_t){0.f, 0.f, 0.f, 0.f};

    for (int kk = 0; kk < 8; ++kk) {
        bf16x8_t ah = *reinterpret_cast<const bf16x8_t*>(Ahi + kk * 32 + g * 8);
        bf16x8_t al = *reinterpret_cast<const bf16x8_t*>(Alo + kk * 32 + g * 8);
        const unsigned short* bb = Bhi + kk * 8192 + (l & 15) * 32 + g * 8;
        const unsigned short* bL = Blo + kk * 8192 + (l & 15) * 32 + g * 8;
        #pragma unroll
        for (int ct = 0; ct < 16; ++ct) {
            bf16x8_t bhv = *reinterpret_cast<const bf16x8_t*>(bb + ct * 512);
            bf16x8_t blv = *reinterpret_cast<const bf16x8_t*>(bL + ct * 512);
            acc[ct] = __builtin_amdgcn_mfma_f32_16x16x32_bf16(ah, bhv, acc[ct], 0, 0, 0);
            acc[ct] = __builtin_amdgcn_mfma_f32_16x16x32_bf16(ah, blv, acc[ct], 0, 0, 0);
            acc[ct] = __builtin_amdgcn_mfma_f32_16x16x32_bf16(al, bhv, acc[ct], 0, 0, 0);
        }
    }

    float part0 = 0.f, part1 = 0.f;
    int r0 = row0 + g * 4;
    #pragma unroll
    for (int ct = 0; ct < 16; ++ct) {
        int col = ct * 16 + (l & 15);
        float b = bp[col], w = wp2v[col];
        #pragma unroll
        for (int i = 0; i < 4; ++i) {
            int r = r0 + i;
            if (r < 2 * NN) {
                float x = acc[ct][i] + b;
                float tnh = 1.f - 2.f / (__expf(2.f * x) + 1.f);
                float v = tnh * w;
                if (i & 1) part1 += v; else part0 += v;
            }
        }
    }
    #pragma unroll
    for (int d = 1; d < 64; d <<= 1) {
        part0 += __shfl_xor(part0, d, 64);
        part1 += __shfl_xor(part1, d, 64);
    }
    __shared__ float red[4][2];
    if (l == 0) { red[wv][0] = part0; red[wv][1] = part1; }
    __syncthreads();
    if (t == 0) {
        atomicAdd(wacc + 0, red[0][0] + red[1][0] + red[2][0] + red[3][0]);
        atomicAdd(wacc + 1, red[0][1] + red[1][1] + red[2][1] + red[3][1]);
    }
}

// ---------------------------------------------------------------------------
__global__ __launch_bounds__(256)
void combine_kernel(const unsigned short* __restrict__ hhi1, const unsigned short* __restrict__ hlo1,
                    const unsigned short* __restrict__ hhi2, const unsigned short* __restrict__ hlo2,
                    const float* __restrict__ wacc, float* __restrict__ out) {
    int idx = blockIdx.x * blockDim.x + threadIdx.x;   // over NN*64 groups of 4
    if (idx >= NN * 64) return;
    float w0 = wacc[0] * (1.f / 30000.f), w1 = wacc[1] * (1.f / 30000.f);
    float mx = fmaxf(w0, w1);
    float e0 = __expf(w0 - mx), e1 = __expf(w1 - mx);
    float inv = 1.f / (e0 + e1);
    float b0 = e0 * inv, b1 = e1 * inv;
    int base = idx * 4;
    ushort4 h1v = *reinterpret_cast<const ushort4*>(hhi1 + base);
    ushort4 l1v = *reinterpret_cast<const ushort4*>(hlo1 + base);
    ushort4 h2v = *reinterpret_cast<const ushort4*>(hhi2 + base);
    ushort4 l2v = *reinterpret_cast<const ushort4*>(hlo2 + base);
    float4 o;
    o.x = b0 * (bf2f(h1v.x) + bf2f(l1v.x)) + b1 * (bf2f(h2v.x) + bf2f(l2v.x));
    o.y = b0 * (bf2f(h1v.y) + bf2f(l1v.y)) + b1 * (bf2f(h2v.y) + bf2f(l2v.y));
    o.z = b0 * (bf2f(h1v.z) + bf2f(l1v.z)) + b1 * (bf2f(h2v.z) + bf2f(l2v.z));
    o.w = b0 * (bf2f(h1v.w) + bf2f(l1v.w)) + b1 * (bf2f(h2v.w) + bf2f(l2v.w));
    *reinterpret_cast<float4*>(out + base) = o;
}

// ---------------------------------------------------------------------------
extern "C" void kernel_launch(void* const* d_in, const int* in_sizes, int n_in,
                              void* d_out, int out_size, void* d_ws, size_t ws_size,
                              hipStream_t stream) {
    const float* embed_h = (const float*)d_in[0];
    const float* gru_h   = (const float*)d_in[1];
    const float* embed_o = (const float*)d_in[2];
    const float* gru_o   = (const float*)d_in[3];
    const float* W_src1  = (const float*)d_in[4];
    const float* a1      = (const float*)d_in[6];
    const float* W_in2   = (const float*)d_in[7];
    const float* a2      = (const float*)d_in[8];
    const float* Wp1     = (const float*)d_in[9];
    const float* bp1     = (const float*)d_in[10];
    const float* wp2     = (const float*)d_in[11];
    const float* W_dst1  = (const float*)d_in[5];
    const int*   e1_src  = (const int*)d_in[12];
    const int*   e2_src  = (const int*)d_in[14];
    float* out = (float*)d_out;

    float* ws = (float*)d_ws;
    float* zs = ws;                               // [0, ZEL) f32
    float* z2 = ws + (size_t)ZEL;                 // [ZEL, 2ZEL) f32
    // h1 hi/lo occupy [2ZEL, 3ZEL) float-equivs as ushorts
    unsigned short* hhi1 = (unsigned short*)(ws + (size_t)2 * ZEL);
    unsigned short* hlo1 = hhi1 + (size_t)ZEL;
    // h2 hi/lo reuse zs region (zs dead after agg layer-1)
    unsigned short* hhi2 = (unsigned short*)ws;
    unsigned short* hlo2 = hhi2 + (size_t)ZEL;

    float* tail  = ws + (size_t)3 * ZEL;
    float* ssrc  = tail;                 // NN*4
    float* sdst  = ssrc + NN * 4;
    float* ssrc2 = ssrc + NN * 8;
    float* sdst2 = ssrc + NN * 12;
    float* u1    = ssrc + NN * 16;
    float* u2    = u1 + 1024;
    float* wacc  = u2 + 1024;
    unsigned short* Bhi1 = (unsigned short*)(wacc + 2);
    unsigned short* Blo1 = Bhi1 + 65536;
    unsigned short* Bhi2 = Blo1 + 65536;
    unsigned short* Blo2 = Bhi2 + 65536;
    unsigned short* Bhip = Blo2 + 65536;
    unsigned short* Blop = Bhip + 65536;

    convert_w<<<256, 256, 0, stream>>>(W_src1, 0, Bhi1, Blo1);
    convert_w<<<256, 256, 0, stream>>>(W_in2,  0, Bhi2, Blo2);
    convert_w<<<256, 256, 0, stream>>>(Wp1,    1, Bhip, Blop);
    prep_u<<<1, 256, 0, stream>>>(W_dst1, a1, u1);
    prep_u<<<1, 256, 0, stream>>>(W_in2,  a2, u2);

    int gemm_blocks = (NN + 63) / 64;
    gemm_nodes<<<gemm_blocks, 256, 0, stream>>>(embed_h, gru_h, Bhi1, Blo1, zs);
    gemm_nodes<<<gemm_blocks, 256, 0, stream>>>(embed_o, gru_o, Bhi2, Blo2, z2);

    int wave_blocks = (NN * 64 + 255) / 256;
    scores_kernel<<<wave_blocks, 256, 0, stream>>>(zs, z2, embed_o, gru_o, a1, a2,
                                                   u1, u2, ssrc, sdst, ssrc2, sdst2);

    agg_kernel<<<wave_blocks, 256, 0, stream>>>(zs, ssrc, sdst, e1_src, hhi1, hlo1);
    agg_kernel<<<wave_blocks, 256, 0, stream>>>(z2, ssrc2, sdst2, e2_src, hhi2, hlo2);

    hipMemsetAsync(wacc, 0, 2 * sizeof(float), stream);
    gemm_proj<<<(2 * NN + 63) / 64, 256, 0, stream>>>(hhi1, hlo1, hhi2, hlo2,
                                                      Bhip, Blop, bp1, wp2, wacc);

    combine_kernel<<<(NN * 64 + 255) / 256, 256, 0, stream>>>(hhi1, hlo1, hhi2, hlo2,
                                                              wacc, out);
}